// Round 17
// baseline (107.641 us; speedup 1.0000x reference)
//
#include <hip/hip_runtime.h>
#include <stdint.h>
#include <math.h>

#define FDIM 126
#define TPB 256
#define RPB 32              // rows per block = 4 waves * 8 rows
#define BEXT(u, j) ((int)(int8_t)((u) >> ((j) * 8)))

// numpy pairwise_sum tree (n=126), f64 — used by v15 fallback general path.
template <typename F>
__device__ __forceinline__ double pw126d(F a) {
    #pragma clang fp contract(off)
    double r0=a(0), r1=a(1), r2=a(2), r3=a(3), r4=a(4), r5=a(5), r6=a(6), r7=a(7);
    for (int i = 8; i < 120; i += 8) {
        r0 += a(i);   r1 += a(i+1); r2 += a(i+2); r3 += a(i+3);
        r4 += a(i+4); r5 += a(i+5); r6 += a(i+6); r7 += a(i+7);
    }
    double res = ((r0 + r1) + (r2 + r3)) + ((r4 + r5) + (r6 + r7));
    res += a(120); res += a(121); res += a(122); res += a(123); res += a(124); res += a(125);
    return res;
}

// ============ K0: pack conv_w sign/nonzero masks (1 block) ============
__global__ __launch_bounds__(TPB) void bnn_packw(
    const float* __restrict__ conv_w, ulonglong2* __restrict__ wbuf)
{
    const int t = threadIdx.x, lane = t & 63, wv = t >> 6;
    for (int r = wv; r < FDIM; r += 4) {
        const float* wr = conv_w + (size_t)r * FDIM;
        float v0 = wr[lane];
        float v1 = (lane < FDIM - 64) ? wr[64 + lane] : 0.f;
        uint64_t ss0 = __ballot(v0 < 0.f);
        uint64_t nn0 = __ballot(v0 != 0.f);
        uint64_t ss1 = __ballot(v1 < 0.f);
        uint64_t nn1 = __ballot(v1 != 0.f);
        if (lane == 0) {
            wbuf[r]        = make_ulonglong2(ss0, ss1);
            wbuf[FDIM + r] = make_ulonglong2(nn0, nn1);
        }
    }
}

// ============ K1: fused pack + wave-cooperative compute (8 lanes/row) ============
// numpy pairwise tree maps to 8 lanes: lane j owns channels j+8k (k<15), combine
// via shfl_xor butterfly (IEEE add commutes -> bit-exact), 6 tail adds via shfl.
__global__ __launch_bounds__(TPB) void bnn_fused(
    const float* __restrict__ x,
    const ulonglong2* __restrict__ wbuf,
    const float* __restrict__ gn1_w, const float* __restrict__ gn1_b,
    const float* __restrict__ gn2_w, const float* __restrict__ gn2_b,
    const float* __restrict__ lin_w, const float* __restrict__ lin_b,
    const float* __restrict__ gn3_w, const float* __restrict__ gn3_b,
    float* __restrict__ out, int nrows)
{
    #pragma clang fp contract(off)
    __shared__ ulonglong2 s_ws[FDIM];
    __shared__ ulonglong2 s_wn[FDIM];
    __shared__ float2 s_g1[FDIM];
    __shared__ float2 s_g2[FDIM];
    __shared__ int8_t s_sl0[128];
    __shared__ int8_t s_sl1[128];
    __shared__ int s_flags;            // 2: gn1 nontrivial, 4: gn2 nontrivial

    const int t = threadIdx.x;
    const int lane = t & 63;
    const int wv = t >> 6;
    const int grp = lane >> 3;         // 8 groups per wave
    const int j = lane & 7;            // lane-in-group = numpy accumulator index
    const int gbase = lane & ~7;       // first lane of my group

    if (t == 0) s_flags = 0;
    __syncthreads();

    if (t < 128) { s_sl0[t] = 0; s_sl1[t] = 0; }
    if (t < FDIM) {
        s_ws[t] = wbuf[t];
        s_wn[t] = wbuf[FDIM + t];
        float g1wv = gn1_w[t], g1bv = gn1_b[t];
        float g2wv = gn2_w[t], g2bv = gn2_b[t];
        s_g1[t] = make_float2(g1wv, g1bv);
        s_g2[t] = make_float2(g2wv, g2bv);
        if (g1wv != 1.f || g1bv != 0.f) atomicOr(&s_flags, 2);
        if (g2wv != 1.f || g2bv != 0.f) atomicOr(&s_flags, 4);
        float l0 = lin_w[t], l1 = lin_w[FDIM + t];
        s_sl0[t] = (int8_t)((l0 > 0.f) - (l0 < 0.f));
        s_sl1[t] = (int8_t)((l1 > 0.f) - (l1 < 0.f));
    }
    __syncthreads();
    const int flags = s_flags;

    // ---- pack this wave's 8 rows; each lane captures its own group's masks ----
    const int64_t rbase = (int64_t)blockIdx.x * RPB + wv * 8;
    uint64_t xs0 = 0, xs1 = 0, xn0 = 0, xn1 = 0;
    #pragma unroll
    for (int k = 0; k < 8; ++k) {
        int64_t r = rbase + k;
        bool ok = r < (int64_t)nrows;              // uniform across wave
        const float* xr = x + r * FDIM;
        float v0 = ok ? xr[lane] : 0.f;
        float v1 = (ok && lane < FDIM - 64) ? xr[64 + lane] : 0.f;
        uint64_t ss0 = __ballot(v0 < 0.f);         // same value in all lanes
        uint64_t nn0 = __ballot(v0 != 0.f);
        uint64_t ss1 = __ballot(v1 < 0.f);
        uint64_t nn1 = __ballot(v1 != 0.f);
        if (k == grp) { xs0 = ss0; xn0 = nn0; xs1 = ss1; xn1 = nn1; }
    }
    const int64_t row = rbase + grp;
    const bool rowOK = row < (int64_t)nrows;

    // ---- h for my 16 channels c = j + 8k (k=15 is the tail 120+j, lanes j<6) ----
    // unified wn-masked form (PROVEN bit-exact, v11/round-12)
    int hk[16];
    int sump = 0;
    #pragma unroll
    for (int k = 0; k < 16; ++k) {
        const int c = j + 8 * k;
        const bool has = (k < 15) || (j < 6);
        ulonglong2 w  = has ? s_ws[c] : make_ulonglong2(0, 0);
        ulonglong2 wn = has ? s_wn[c] : make_ulonglong2(0, 0);
        uint64_t m0 = xn0 & wn.x, m1 = xn1 & wn.y;
        int pm = __popcll(m0) + __popcll(m1);
        int pc = __popcll((xs0 ^ w.x) & m0) + __popcll((xs1 ^ w.y) & m1);
        int hv = has ? (pm - 2 * pc) : 0;
        hk[k] = hv;
        sump += hv;
    }
    // integer row sum (exact, any order)
    int sum = sump;
    sum += __shfl_xor(sum, 1); sum += __shfl_xor(sum, 2); sum += __shfl_xor(sum, 4);

    // tree helpers: butterfly combine (commutative-exact) + sequential 6-term tail
    auto treef = [&](float q, float et) -> float {
        #pragma clang fp contract(off)
        float v = q + __shfl_xor(q, 1);
        v = v + __shfl_xor(v, 2);
        v = v + __shfl_xor(v, 4);
        #pragma unroll
        for (int kk = 0; kk < 6; ++kk) v += __shfl(et, gbase + kk, 64);
        return v;
    };
    auto treed = [&](double q, double et) -> double {
        #pragma clang fp contract(off)
        double v = q + __shfl_xor(q, 1);
        v = v + __shfl_xor(v, 2);
        v = v + __shfl_xor(v, 4);
        #pragma unroll
        for (int kk = 0; kk < 6; ++kk) v += __shfl(et, gbase + kk, 64);
        return v;
    };

    // ---- GN1 stats in f32 (np.mean keeps dtype); PROVEN mixed-precision chain ----
    const float mu1f = (float)sum / 126.0f;
    float qf, etf = 0.f;
    {
        float e = (float)hk[0] - mu1f; qf = e * e;        // r_j = a(j) init
        #pragma unroll
        for (int k = 1; k < 15; ++k) { e = (float)hk[k] - mu1f; qf += e * e; }
        if (j < 6) { e = (float)hk[15] - mu1f; etf = e * e; }
    }
    const float var1f = treef(qf, etf) / 126.0f;
    const double r1 = 1.0 / sqrt((double)var1f + 1e-5);   // f64 literal promotes

    auto c1ofh = [&](int hv) -> double {
        #pragma clang fp contract(off)
        float e32 = (float)hv - mu1f;
        double y = (double)e32 * r1;
        return fmin(fmax(y, -1.0), 1.0);
    };

    int ip0 = 0, ip1 = 0;
    if (!(flags & 6)) {
        // ---- mu2: f64 np pairwise tree across the 8 lanes ----
        double qd = c1ofh(hk[0]);
        #pragma unroll
        for (int k = 1; k < 15; ++k) qd += c1ofh(hk[k]);
        double etd = (j < 6) ? c1ofh(hk[15]) : 0.0;
        const double mu2 = treed(qd, etd) / 126.0;

        // ---- integer thresholds via monotone binary search (PROVEN v15) ----
        const double c127 = c1ofh(127);
        int lo1 = -127, hi1 = 127, lo2 = -127, hi2 = 127;
        #pragma unroll
        for (int it = 0; it < 8; ++it) {
            int m1 = (lo1 + hi1) >> 1;
            bool ge = (c1ofh(m1) >= mu2);
            hi1 = ge ? m1 : hi1;  lo1 = ge ? lo1 : m1 + 1;
            int m2 = (lo2 + hi2) >> 1;
            bool gt = (c1ofh(m2) > mu2);
            hi2 = gt ? m2 : hi2;  lo2 = gt ? lo2 : m2 + 1;
        }
        const int vge = (c127 >= mu2) ? lo1 : 128;
        const int vgt = (c127 >  mu2) ? lo2 : 128;

        #pragma unroll
        for (int k = 0; k < 16; ++k) {
            const int c = j + 8 * k;
            const bool has = (k < 15) || (j < 6);
            int hv = hk[k];
            int hb = has ? ((hv >= vgt) - (hv < vge)) : 0;
            ip0 += hb * (int)s_sl0[c & 127];
            ip1 += hb * (int)s_sl1[c & 127];
        }
    } else {
        // ---- general path (not taken for this data): same np mirror, cooperative ----
        auto c1g = [&](int hv, int c) -> double {
            #pragma clang fp contract(off)
            float e32 = (float)hv - mu1f;
            float2 g = s_g1[c];
            double y = (((double)e32 * r1) * (double)g.x) + (double)g.y;
            return fmin(fmax(y, -1.0), 1.0);
        };
        double qd = c1g(hk[0], j);
        #pragma unroll
        for (int k = 1; k < 15; ++k) qd += c1g(hk[k], j + 8 * k);
        double etd = (j < 6) ? c1g(hk[15], 120 + j) : 0.0;
        const double mu2 = treed(qd, etd) / 126.0;

        double q2 = 0.0, et2 = 0.0;
        {
            double e2 = c1g(hk[0], j) - mu2; q2 = e2 * e2;
            #pragma unroll
            for (int k = 1; k < 15; ++k) { double e2b = c1g(hk[k], j + 8 * k) - mu2; q2 += e2b * e2b; }
            if (j < 6) { double e2b = c1g(hk[15], 120 + j) - mu2; et2 = e2b * e2b; }
        }
        const double var2 = treed(q2, et2) / 126.0;
        const double r2 = 1.0 / sqrt(var2 + 1e-5);
        #pragma unroll
        for (int k = 0; k < 16; ++k) {
            const int c = j + 8 * k;
            const bool has = (k < 15) || (j < 6);
            if (has) {
                double e2 = c1g(hk[k], c) - mu2;
                float2 g2 = s_g2[c];
                double z = ((e2 * r2) * (double)g2.x) + (double)g2.y;
                int hb = (z > 0.0) - (z < 0.0);
                ip0 += hb * (int)s_sl0[c];
                ip1 += hb * (int)s_sl1[c];
            }
        }
    }
    // group-sum the integer dots (exact)
    ip0 += __shfl_xor(ip0, 1); ip0 += __shfl_xor(ip0, 2); ip0 += __shfl_xor(ip0, 4);
    ip1 += __shfl_xor(ip1, 1); ip1 += __shfl_xor(ip1, 2); ip1 += __shfl_xor(ip1, 4);

    // ---- BNNLinear + GN3 in f64 (PROVEN); lane 0 of each group writes ----
    if (rowOK && j == 0) {
        double o0 = (double)ip0 + (double)lin_b[0];
        double o1 = (double)ip1 + (double)lin_b[1];
        double mu = (o0 + o1) / 2.0;
        double d0 = o0 - mu, d1 = o1 - mu;
        double var = ((d0 * d0) + (d1 * d1)) / 2.0;
        double r3 = 1.0 / sqrt(var + 1e-5);
        double q0 = ((d0 * r3) * (double)gn3_w[0]) + (double)gn3_b[0];
        double q1 = ((d1 * r3) * (double)gn3_w[1]) + (double)gn3_b[1];
        reinterpret_cast<float2*>(out)[row] = make_float2((float)q0, (float)q1);
    }
}

// ============ Fallback: v15 single-kernel (proven), if ws too small ============
__global__ __launch_bounds__(TPB) void bnn_v15(
    const float* __restrict__ x,
    const float* __restrict__ conv_w,
    const float* __restrict__ gn1_w, const float* __restrict__ gn1_b,
    const float* __restrict__ gn2_w, const float* __restrict__ gn2_b,
    const float* __restrict__ lin_w, const float* __restrict__ lin_b,
    const float* __restrict__ gn3_w, const float* __restrict__ gn3_b,
    float* __restrict__ out, int nrows)
{
    #pragma clang fp contract(off)
    __shared__ ulonglong2 s_ws[FDIM];
    __shared__ ulonglong2 s_wn[FDIM];
    __shared__ float2 s_g1[FDIM];
    __shared__ float2 s_g2[FDIM];
    __shared__ int8_t s_sl0[128];
    __shared__ int8_t s_sl1[128];
    __shared__ int s_flags;
    __shared__ __align__(16) uint8_t s_pool[TPB * 128];

    ulonglong2* s_xs = (ulonglong2*)s_pool;
    ulonglong2* s_xn = (ulonglong2*)(s_pool + 4096);
    uint32_t*   s_h  = (uint32_t*)s_pool;

    const int t = threadIdx.x;
    const int lane = t & 63;
    const int wv = t >> 6;
    const int64_t row0 = (int64_t)blockIdx.x * TPB;
    const int64_t row = row0 + t;
    const bool rowOK = row < (int64_t)nrows;

    if (t == 0) s_flags = 0;
    __syncthreads();

    for (int r = wv; r < FDIM; r += 4) {
        const float* wr = conv_w + (size_t)r * FDIM;
        float v0 = wr[lane];
        float v1 = (lane < FDIM - 64) ? wr[64 + lane] : 0.f;
        uint64_t ss0 = __ballot(v0 < 0.f);
        uint64_t nn0 = __ballot(v0 != 0.f);
        uint64_t ss1 = __ballot(v1 < 0.f);
        uint64_t nn1 = __ballot(v1 != 0.f);
        if (lane == 0) {
            s_ws[r] = make_ulonglong2(ss0, ss1);
            s_wn[r] = make_ulonglong2(nn0, nn1);
            if (__popcll(nn0) + __popcll(nn1) != FDIM) atomicOr(&s_flags, 1);
        }
    }
    #pragma unroll 4
    for (int k = 0; k < 64; ++k) {
        int lr = (wv << 6) + k;
        int64_t r = row0 + lr;
        bool ok = r < (int64_t)nrows;
        const float* xr = x + r * FDIM;
        float v0 = ok ? xr[lane] : 0.f;
        float v1 = (ok && lane < FDIM - 64) ? xr[64 + lane] : 0.f;
        uint64_t ss0 = __ballot(v0 < 0.f);
        uint64_t nn0 = __ballot(v0 != 0.f);
        uint64_t ss1 = __ballot(v1 < 0.f);
        uint64_t nn1 = __ballot(v1 != 0.f);
        if (lane == 0) {
            s_xs[lr] = make_ulonglong2(ss0, ss1);
            s_xn[lr] = make_ulonglong2(nn0, nn1);
        }
    }
    if (t < FDIM) {
        float g1wv = gn1_w[t], g1bv = gn1_b[t];
        float g2wv = gn2_w[t], g2bv = gn2_b[t];
        s_g1[t] = make_float2(g1wv, g1bv);
        s_g2[t] = make_float2(g2wv, g2bv);
        if (g1wv != 1.f || g1bv != 0.f) atomicOr(&s_flags, 2);
        if (g2wv != 1.f || g2bv != 0.f) atomicOr(&s_flags, 4);
        float l0 = lin_w[t], l1 = lin_w[FDIM + t];
        s_sl0[t] = (int8_t)((l0 > 0.f) - (l0 < 0.f));
        s_sl1[t] = (int8_t)((l1 > 0.f) - (l1 < 0.f));
    }
    __syncthreads();
    const int flags = s_flags;

    const ulonglong2 xs = s_xs[t];
    const ulonglong2 xn = s_xn[t];
    const int Kx = __popcll(xn.x) + __popcll(xn.y);
    __syncthreads();

    int sum = 0;
    if (!(flags & 1)) {
        for (int g = 0; g < 32; ++g) {
            uint32_t pack = 0;
            #pragma unroll
            for (int jj = 0; jj < 4; ++jj) {
                int cc = 4 * g + jj;
                if (cc < FDIM) {
                    ulonglong2 w = s_ws[cc];
                    int pc = __popcll((xs.x ^ w.x) & xn.x) + __popcll((xs.y ^ w.y) & xn.y);
                    int h = Kx - 2 * pc;
                    sum += h;
                    pack |= (uint32_t)(h & 255) << (8 * jj);
                }
            }
            s_h[g * TPB + t] = pack;
        }
    } else {
        for (int g = 0; g < 32; ++g) {
            uint32_t pack = 0;
            #pragma unroll
            for (int jj = 0; jj < 4; ++jj) {
                int cc = 4 * g + jj;
                if (cc < FDIM) {
                    ulonglong2 w = s_ws[cc];
                    ulonglong2 wn = s_wn[cc];
                    uint64_t m0 = xn.x & wn.x, m1 = xn.y & wn.y;
                    int pm = __popcll(m0) + __popcll(m1);
                    int pc = __popcll((xs.x ^ w.x) & m0) + __popcll((xs.y ^ w.y) & m1);
                    int h = pm - 2 * pc;
                    sum += h;
                    pack |= (uint32_t)(h & 255) << (8 * jj);
                }
            }
            s_h[g * TPB + t] = pack;
        }
    }

    auto hdw = [&](int g) -> uint32_t { return s_h[g * TPB + t]; };
    auto hget = [&](int i) -> int { return BEXT(hdw(i >> 2), i & 3); };

    const float mu1f = (float)sum / 126.0f;
    float var1f;
    {
        uint32_t u0 = hdw(0), u1 = hdw(1);
        float e;
        e = (float)BEXT(u0,0) - mu1f; float q0 = e*e;
        e = (float)BEXT(u0,1) - mu1f; float q1 = e*e;
        e = (float)BEXT(u0,2) - mu1f; float q2 = e*e;
        e = (float)BEXT(u0,3) - mu1f; float q3 = e*e;
        e = (float)BEXT(u1,0) - mu1f; float q4 = e*e;
        e = (float)BEXT(u1,1) - mu1f; float q5 = e*e;
        e = (float)BEXT(u1,2) - mu1f; float q6 = e*e;
        e = (float)BEXT(u1,3) - mu1f; float q7 = e*e;
        for (int k = 1; k < 15; ++k) {
            uint32_t a0 = hdw(2*k), a1 = hdw(2*k + 1);
            e = (float)BEXT(a0,0) - mu1f; q0 += e*e;
            e = (float)BEXT(a0,1) - mu1f; q1 += e*e;
            e = (float)BEXT(a0,2) - mu1f; q2 += e*e;
            e = (float)BEXT(a0,3) - mu1f; q3 += e*e;
            e = (float)BEXT(a1,0) - mu1f; q4 += e*e;
            e = (float)BEXT(a1,1) - mu1f; q5 += e*e;
            e = (float)BEXT(a1,2) - mu1f; q6 += e*e;
            e = (float)BEXT(a1,3) - mu1f; q7 += e*e;
        }
        float res = ((q0 + q1) + (q2 + q3)) + ((q4 + q5) + (q6 + q7));
        uint32_t u30 = hdw(30), u31 = hdw(31);
        e = (float)BEXT(u30,0) - mu1f; res += e*e;
        e = (float)BEXT(u30,1) - mu1f; res += e*e;
        e = (float)BEXT(u30,2) - mu1f; res += e*e;
        e = (float)BEXT(u30,3) - mu1f; res += e*e;
        e = (float)BEXT(u31,0) - mu1f; res += e*e;
        e = (float)BEXT(u31,1) - mu1f; res += e*e;
        var1f = res / 126.0f;
    }
    const double r1 = 1.0 / sqrt((double)var1f + 1e-5);

    auto c1ofh = [&](int hv) -> double {
        #pragma clang fp contract(off)
        float e32 = (float)hv - mu1f;
        double y = (double)e32 * r1;
        return fmin(fmax(y, -1.0), 1.0);
    };

    int ip0 = 0, ip1 = 0;
    if (!(flags & 6)) {
        double mu2;
        {
            uint32_t u0 = hdw(0), u1 = hdw(1);
            double q0 = c1ofh(BEXT(u0,0)), q1 = c1ofh(BEXT(u0,1));
            double q2 = c1ofh(BEXT(u0,2)), q3 = c1ofh(BEXT(u0,3));
            double q4 = c1ofh(BEXT(u1,0)), q5 = c1ofh(BEXT(u1,1));
            double q6 = c1ofh(BEXT(u1,2)), q7 = c1ofh(BEXT(u1,3));
            for (int k = 1; k < 15; ++k) {
                uint32_t a0 = hdw(2*k), a1 = hdw(2*k + 1);
                q0 += c1ofh(BEXT(a0,0)); q1 += c1ofh(BEXT(a0,1));
                q2 += c1ofh(BEXT(a0,2)); q3 += c1ofh(BEXT(a0,3));
                q4 += c1ofh(BEXT(a1,0)); q5 += c1ofh(BEXT(a1,1));
                q6 += c1ofh(BEXT(a1,2)); q7 += c1ofh(BEXT(a1,3));
            }
            double res = ((q0 + q1) + (q2 + q3)) + ((q4 + q5) + (q6 + q7));
            uint32_t u30 = hdw(30), u31 = hdw(31);
            res += c1ofh(BEXT(u30,0)); res += c1ofh(BEXT(u30,1));
            res += c1ofh(BEXT(u30,2)); res += c1ofh(BEXT(u30,3));
            res += c1ofh(BEXT(u31,0)); res += c1ofh(BEXT(u31,1));
            mu2 = res / 126.0;
        }
        const double c127 = c1ofh(127);
        int lo1 = -127, hi1 = 127, lo2 = -127, hi2 = 127;
        #pragma unroll
        for (int it = 0; it < 8; ++it) {
            int m1 = (lo1 + hi1) >> 1;
            bool ge = (c1ofh(m1) >= mu2);
            hi1 = ge ? m1 : hi1;  lo1 = ge ? lo1 : m1 + 1;
            int m2 = (lo2 + hi2) >> 1;
            bool gt = (c1ofh(m2) > mu2);
            hi2 = gt ? m2 : hi2;  lo2 = gt ? lo2 : m2 + 1;
        }
        const int vge = (c127 >= mu2) ? lo1 : 128;
        const int vgt = (c127 >  mu2) ? lo2 : 128;

        for (int g = 0; g < 31; ++g) {
            uint32_t u = hdw(g);
            #pragma unroll
            for (int jj = 0; jj < 4; ++jj) {
                int c = 4 * g + jj;
                int hv = BEXT(u, jj);
                int hb = (hv >= vgt) - (hv < vge);
                ip0 += hb * (int)s_sl0[c];
                ip1 += hb * (int)s_sl1[c];
            }
        }
        {
            uint32_t u = hdw(31);
            #pragma unroll
            for (int jj = 0; jj < 2; ++jj) {
                int hv = BEXT(u, jj);
                int hb = (hv >= vgt) - (hv < vge);
                ip0 += hb * (int)s_sl0[124 + jj];
                ip1 += hb * (int)s_sl1[124 + jj];
            }
        }
    } else {
        auto c1f = [&](int i) -> double {
            #pragma clang fp contract(off)
            float e32 = (float)hget(i) - mu1f;
            float2 g = s_g1[i];
            double y = (((double)e32 * r1) * (double)g.x) + (double)g.y;
            return fmin(fmax(y, -1.0), 1.0);
        };
        const double mu2 = pw126d(c1f) / 126.0;
        const double var2 = pw126d([&](int i) -> double {
            #pragma clang fp contract(off)
            double e2 = c1f(i) - mu2;
            return e2 * e2;
        }) / 126.0;
        const double r2 = 1.0 / sqrt(var2 + 1e-5);
        for (int c = 0; c < FDIM; ++c) {
            double e2 = c1f(c) - mu2;
            float2 g2 = s_g2[c];
            double z = ((e2 * r2) * (double)g2.x) + (double)g2.y;
            int hb = (z > 0.0) - (z < 0.0);
            ip0 += hb * (int)s_sl0[c];
            ip1 += hb * (int)s_sl1[c];
        }
    }

    if (rowOK) {
        double o0 = (double)ip0 + (double)lin_b[0];
        double o1 = (double)ip1 + (double)lin_b[1];
        double mu = (o0 + o1) / 2.0;
        double d0 = o0 - mu, d1 = o1 - mu;
        double var = ((d0 * d0) + (d1 * d1)) / 2.0;
        double r3 = 1.0 / sqrt(var + 1e-5);
        double q0 = ((d0 * r3) * (double)gn3_w[0]) + (double)gn3_b[0];
        double q1 = ((d1 * r3) * (double)gn3_w[1]) + (double)gn3_b[1];
        reinterpret_cast<float2*>(out)[row] = make_float2((float)q0, (float)q1);
    }
}

extern "C" void kernel_launch(void* const* d_in, const int* in_sizes, int n_in,
                              void* d_out, int out_size, void* d_ws, size_t ws_size,
                              hipStream_t stream) {
    const float* x      = (const float*)d_in[0];
    const float* conv_w = (const float*)d_in[1];
    const float* gn1_w  = (const float*)d_in[2];
    const float* gn1_b  = (const float*)d_in[3];
    const float* gn2_w  = (const float*)d_in[4];
    const float* gn2_b  = (const float*)d_in[5];
    const float* lin_w  = (const float*)d_in[6];
    const float* lin_b  = (const float*)d_in[7];
    const float* gn3_w  = (const float*)d_in[8];
    const float* gn3_b  = (const float*)d_in[9];
    float* out = (float*)d_out;

    int nrows = in_sizes[0] / FDIM;

    if (d_ws != nullptr && ws_size >= 2 * FDIM * sizeof(ulonglong2)) {
        ulonglong2* wbuf = (ulonglong2*)d_ws;
        bnn_packw<<<1, TPB, 0, stream>>>(conv_w, wbuf);
        int nblocks = (nrows + RPB - 1) / RPB;
        bnn_fused<<<nblocks, TPB, 0, stream>>>(x, wbuf, gn1_w, gn1_b, gn2_w, gn2_b,
                                               lin_w, lin_b, gn3_w, gn3_b, out, nrows);
    } else {
        int nblocks = (nrows + TPB - 1) / TPB;
        bnn_v15<<<nblocks, TPB, 0, stream>>>(x, conv_w, gn1_w, gn1_b, gn2_w, gn2_b,
                                             lin_w, lin_b, gn3_w, gn3_b, out, nrows);
    }
}